// Round 12
// baseline (217.353 us; speedup 1.0000x reference)
//
#include <hip/hip_runtime.h>
#include <hip/hip_bf16.h>
#include <stdint.h>
#include <stddef.h>

// DCNv2 forward: B=4, H=W=96, C=256, F=256, K=9 (3x3, same, stride1, dil1), DG=1.
// R5/R8/R11: fusion failed 3x. R7: swizzle (conflicts->0). R9: XCD swizzle (-5us).
// R12: atomic-free k_omgemm. R16: k_omgemm BK=128 + k_gemm paired-N XCD map -> 201us.
// R17: algebraic restructure (GEMM and bilinear commute) CRASHED the container --
//   padded-G layout needed 202.7MB ws vs the 195.58MB footprint every passing round
//   used -> G-stores overflowed d_ws. Also had an OOB A-read on the last M-tile.
// R18: same restructure, exact old footprint. G stored UNPADDED [9][36864][256] bf16
//   (= old cols byte size). k_gemmG grid (288,9), XCD-contig on m-tiles (288%8==0 ->
//   same px slice -> same XCD for all 9 planes, matching k_combine's partition);
//   A rows read xp interior (no OOB). k_combine clamps corners to the interior with
//   wgt=0 (never touches halo; 0*finite=0). out[p,f] = sum_k sum_j w_j*G_k[r_j,f].

namespace {
constexpr int H  = 96, W = 96, C = 256, F = 256;
constexpr int HP = 98;             // padded spatial dim (1-px zero halo)
constexpr int NP = 4 * 96 * 96;    // 36864 output pixels
constexpr int KC = 9 * 256;        // 2304

constexpr int NB_PAD  = 4 * HP * HP / 8;       // 4802 blocks, 8 px each
constexpr int NB_OMW  = 9 * 32;                // 288
constexpr int NB_WT   = (KC / 64) * (F / 64);  // 144
}

typedef __attribute__((ext_vector_type(8))) short bf16x8;
typedef __attribute__((ext_vector_type(4))) float floatx4;

__device__ __forceinline__ void load_lds16(const void* g, void* l) {
  __builtin_amdgcn_global_load_lds((const __attribute__((address_space(1))) void*)g,
                                   (__attribute__((address_space(3))) void*)l,
                                   16, 0, 0);
}

__device__ __forceinline__ uint32_t pk2(float lo, float hi) {   // v_cvt_pk_bf16_f32 (RNE)
  __hip_bfloat162 t = __float22bfloat162_rn(float2{lo, hi});
  return *reinterpret_cast<uint32_t*>(&t);
}

__device__ __forceinline__ void acc8(uint4 v, float w, float* a) {
  a[0] += w * __uint_as_float(v.x << 16); a[1] += w * __uint_as_float(v.x & 0xffff0000u);
  a[2] += w * __uint_as_float(v.y << 16); a[3] += w * __uint_as_float(v.y & 0xffff0000u);
  a[4] += w * __uint_as_float(v.z << 16); a[5] += w * __uint_as_float(v.z & 0xffff0000u);
  a[6] += w * __uint_as_float(v.w << 16); a[7] += w * __uint_as_float(v.w & 0xffff0000u);
}

// ---------------- k_pad: x fp32 -> xp bf16 with 1-px zero halo ----------------
__global__ __launch_bounds__(256) void k_pad(const float* __restrict__ x,
                                             uint4* __restrict__ xp4) {
  const int tid = threadIdx.x;
  const int sub = tid >> 5, cid = tid & 31;
  const int pp  = blockIdx.x * 8 + sub;
  const int b   = pp / (HP * HP);
  const int r   = pp % (HP * HP);
  const int y   = r / HP, xq = r % HP;
  uint4 o = {0u, 0u, 0u, 0u};
  if (y >= 1 && y <= H && xq >= 1 && xq <= W) {
    const float* src = x + ((size_t)((b * H + (y - 1)) * W + (xq - 1))) * C + cid * 8;
    const float4 v0 = *(const float4*)src;
    const float4 v1 = *(const float4*)(src + 4);
    o.x = pk2(v0.x, v0.y); o.y = pk2(v0.z, v0.w);
    o.z = pk2(v1.x, v1.y); o.w = pk2(v1.z, v1.w);
  }
  xp4[(size_t)pp * 32 + cid] = o;
}

// ---------------- k_wprep: omw repack + wt transpose ----------------
__global__ __launch_bounds__(256) void k_wprep(const float* __restrict__ omk,
                                               const float* __restrict__ kern,
                                               __hip_bfloat16* __restrict__ wom,
                                               __hip_bfloat16* __restrict__ wt) {
  __shared__ float t[64][65];
  const int bi = blockIdx.x, tid = threadIdx.x;

  if (bi < NB_OMW) {                       // ---- omw: [9*256][27] -> [32][2304] ----
    const int kk = bi / 32, oc = bi % 32;
    float v = (oc < 27) ? omk[(size_t)(kk * 256 + tid) * 27 + oc] : 0.f;
    wom[(size_t)oc * KC + kk * 256 + tid] = __float2bfloat16(v);
  } else {                                 // ---- wt: [KC][F] -> [F][KC] bf16 ----
    const int j   = bi - NB_OMW;
    const int kc0 = (j % (KC / 64)) * 64, f0 = (j / (KC / 64)) * 64;
    const int rr = tid >> 6, cc = tid & 63;
#pragma unroll
    for (int i = 0; i < 16; ++i)
      t[rr * 16 + i][cc] = kern[(size_t)(kc0 + rr * 16 + i) * F + f0 + cc];
    __syncthreads();
#pragma unroll
    for (int i = 0; i < 16; ++i) {
      const int frow = rr * 16 + i;
      wt[(size_t)(f0 + frow) * KC + kc0 + cc] = __float2bfloat16(t[cc][frow]);
    }
  }
}

// ---------------- k_omgemm: 64(M)x32(N), BK=128 -> 18 windows, 2-phase dbuf (R16) ----------
__global__ __launch_bounds__(256) void k_omgemm(const __hip_bfloat16* __restrict__ xp,
                                                const __hip_bfloat16* __restrict__ wom,
                                                float* __restrict__ pOm) {
  __shared__ __align__(16) char lds[49152];
  const int tid  = threadIdx.x;
  const int xr   = blockIdx.x;
  const int xs   = (xr & 7) * 72 + (xr >> 3);     // XCD-contiguous over 576 tiles
  const int m0   = xs * 64;
  const int lane = tid & 63, wave = tid >> 6;
  const int quad = lane >> 4, l16 = lane & 15;

  const int srow = tid >> 4;          // 0..15
  const int gchk = (tid & 15) ^ srow; // pre-swizzled global chunk (16B units)

  const __hip_bfloat16* abase[4];
#pragma unroll
  for (int j = 0; j < 4; ++j) {
    const int p  = m0 + srow + j * 16;
    const int b  = p / (H * W);
    const int hw = p % (H * W);
    const int h  = hw / W, w = hw % W;
    abase[j] = xp + ((size_t)(b * HP + h) * HP + w) * C + gchk * 8;
  }
  const __hip_bfloat16* bbase[2];
#pragma unroll
  for (int j = 0; j < 2; ++j)
    bbase[j] = wom + (size_t)(srow + j * 16) * KC + gchk * 8;

  auto stage = [&](int buf, int k0) {
    const int kk = k0 >> 8, c0 = k0 & 255;
    const int aoff = ((kk / 3) * HP + (kk % 3)) * C + c0;
    char* base = &lds[buf * 24576];
#pragma unroll
    for (int j = 0; j < 4; ++j)                 // A rows srow + 16j
      load_lds16(abase[j] + aoff, base + j * 4096 + tid * 16);
#pragma unroll
    for (int j = 0; j < 2; ++j)                 // B rows srow + 16j
      load_lds16(bbase[j] + k0, base + 16384 + j * 4096 + tid * 16);
  };

  floatx4 acc[2];
  acc[0] = (floatx4){0.f, 0.f, 0.f, 0.f};
  acc[1] = (floatx4){0.f, 0.f, 0.f, 0.f};

  stage(0, 0);
  int cur = 0;
#pragma unroll 1
  for (int k0 = 0; k0 < KC; k0 += 128) {
    __syncthreads();
    if (k0 + 128 < KC) stage(cur ^ 1, k0 + 128);
    const char* base = &lds[cur * 24576];

#pragma unroll
    for (int ks = 0; ks < 4; ++ks) {
      const int slot = (((ks * 4 + quad) ^ l16) & 15) * 16;   // byte offset in 256B row
      bf16x8 af = *(const bf16x8*)&base[(wave * 16 + l16) * 256 + slot];
      bf16x8 b0 = *(const bf16x8*)&base[16384 + l16 * 256 + slot];
      bf16x8 b1 = *(const bf16x8*)&base[16384 + (16 + l16) * 256 + slot];
      acc[0] = __builtin_amdgcn_mfma_f32_16x16x32_bf16(af, b0, acc[0], 0, 0, 0);
      acc[1] = __builtin_amdgcn_mfma_f32_16x16x32_bf16(af, b1, acc[1], 0, 0, 0);
    }
    cur ^= 1;
  }

#pragma unroll
  for (int nt = 0; nt < 2; ++nt) {
    const int gm = m0 + wave * 16 + quad * 4;
    const int gn = nt * 16 + l16;
#pragma unroll
    for (int r = 0; r < 4; ++r)
      pOm[(size_t)(gm + r) * 32 + gn] = acc[nt][r];
  }
}

// ---------------- k_gemmG: G_k[p,f] = xp[interior row p] @ kern_k, K=256 ----------------
// G unpadded [9][NP][256] bf16. Grid (288, 9): x = m-tile (XCD-contig transform;
// 288%8==0 -> same px slice lands on same XCD for all 9 planes), y = kernel point.
// 512 thr = 8 waves (2M x 4N), wave 64x64, acc[4][4]. K=256 -> 8 windows BK=32,
// 2-phase dbuf, 48KB LDS. A rows: per-row interior pointer (no OOB); stores exact.
__global__ __launch_bounds__(512) void k_gemmG(const __hip_bfloat16* __restrict__ xp,
                                               const __hip_bfloat16* __restrict__ wt,
                                               __hip_bfloat16* __restrict__ G) {
  __shared__ __align__(16) char lds[49152];   // 2 x {A [128][64B] 8KB, B [256][64B] 16KB}
  const int tid   = threadIdx.x;
  const int xs    = (blockIdx.x & 7) * 36 + (blockIdx.x >> 3);  // XCD-contig over 288
  const int m0    = xs * 128;
  const int kk    = blockIdx.y;               // kernel point 0..8
  const int kbase = kk * 256;
  const int lane  = tid & 63, wave = tid >> 6;
  const int wm = wave >> 2, wn = wave & 3;    // 2M x 4N waves of 64x64
  const int quad = lane >> 4, l16 = lane & 15;

  const int kp = (tid & 3) ^ ((tid >> 3) & 3);
  const int p  = m0 + (tid >> 2);             // my A row (0..NP)
  const int b  = p / (H * W);
  const int hw = p % (H * W);
  const int h  = hw / W, w = hw % W;
  const __hip_bfloat16* asrc = xp + ((size_t)((b * HP + h + 1) * HP) + w + 1) * C + kp * 8;
  const __hip_bfloat16* b0   = wt + (size_t)(tid >> 2) * KC + kbase + kp * 8;
  const __hip_bfloat16* b1   = b0 + (size_t)128 * KC;

  auto stage = [&](int buf, int c0) {
    char* base = &lds[buf * 24576];
    load_lds16(asrc + c0, base + tid * 16);               // A 128x32
    load_lds16(b0 + c0, base + 8192 + tid * 16);          // B f 0..127
    load_lds16(b1 + c0, base + 16384 + tid * 16);         // B f 128..255
  };

  floatx4 acc[4][4];
#pragma unroll
  for (int i = 0; i < 4; ++i)
#pragma unroll
    for (int j = 0; j < 4; ++j) acc[i][j] = (floatx4){0.f, 0.f, 0.f, 0.f};

  const int swq = (quad ^ ((l16 >> 1) & 3)) * 16;

  stage(0, 0);
  int cur = 0;
#pragma unroll 1
  for (int c0 = 0; c0 < 256; c0 += 32) {
    __syncthreads();
    if (c0 + 32 < 256) stage(cur ^ 1, c0 + 32);
    const char* base = &lds[cur * 24576];

    bf16x8 af[4], bfr[4];
#pragma unroll
    for (int mt = 0; mt < 4; ++mt)
      af[mt] = *(const bf16x8*)&base[(wm * 64 + mt * 16 + l16) * 64 + swq];
#pragma unroll
    for (int nt = 0; nt < 4; ++nt)
      bfr[nt] = *(const bf16x8*)&base[8192 + (wn * 64 + nt * 16 + l16) * 64 + swq];
#pragma unroll
    for (int mt = 0; mt < 4; ++mt)
#pragma unroll
      for (int nt = 0; nt < 4; ++nt)
        acc[mt][nt] = __builtin_amdgcn_mfma_f32_16x16x32_bf16(af[mt], bfr[nt], acc[mt][nt], 0, 0, 0);
    cur ^= 1;
  }

  __hip_bfloat16* gp = G + (size_t)kk * NP * 256;
#pragma unroll
  for (int mt = 0; mt < 4; ++mt) {
#pragma unroll
    for (int nt = 0; nt < 4; ++nt) {
      const int gm = m0 + wm * 64 + mt * 16 + quad * 4;
      const int gn = wn * 64 + nt * 16 + l16;
#pragma unroll
      for (int r = 0; r < 4; ++r)
        gp[(size_t)(gm + r) * 256 + gn] = __float2bfloat16(acc[mt][nt][r]);
    }
  }
}

// ---------------- k_combine: bilinear+mask over G planes -> out ----------------
// 8 px/block, 32 thr/px (8 f each). Corners clamped to INTERIOR (wgt=0 when invalid;
// 0*finite==0). Per px: 36 uint4 gathers weighted into fp32 a[8]; +bias; one store.
__global__ __launch_bounds__(256) void k_combine(const uint4* __restrict__ G4,
                                                 const float* __restrict__ pOm,
                                                 const float* __restrict__ om_bias,
                                                 const float* __restrict__ bias,
                                                 float* __restrict__ out) {
  __shared__ float2 s_ow[8][9][4];   // per (px,k,corner): {uint4 row-offset, weight*mask}

  const int tid = threadIdx.x;
  const int sub = tid >> 5, cid = tid & 31;     // px-in-block, 8-f unit
  const int bs  = (blockIdx.x & 7) * 576 + (blockIdx.x >> 3);   // XCD-contiguous

  if (tid < 72) {                               // setup: 8 px x 9 k
    const int ps = tid / 9, k = tid % 9;
    const int p  = bs * 8 + ps;
    const int b  = p / (H * W);
    const int hw = p % (H * W);
    const int h = hw / W, w = hw % W;
    const float dy = om_bias[2 * k]     + pOm[(size_t)p * 32 + 2 * k];
    const float dx = om_bias[2 * k + 1] + pOm[(size_t)p * 32 + 2 * k + 1];
    const float mv = om_bias[18 + k]    + pOm[(size_t)p * 32 + 18 + k];
    const float m  = 2.f / (1.f + __expf(-mv));
    const float sy = (float)(h - 1 + k / 3) + dy;
    const float sx = (float)(w - 1 + k % 3) + dx;
    const float y0f = floorf(sy), x0f = floorf(sx);
    const float fy = sy - y0f, fx = sx - x0f;
    const int y0 = (int)y0f, x0 = (int)x0f;
#pragma unroll
    for (int c2 = 0; c2 < 4; ++c2) {
      const int dy2 = c2 >> 1, dx2 = c2 & 1;
      const int yi = y0 + dy2, xi = x0 + dx2;
      const bool valid = (yi >= 0) & (yi < H) & (xi >= 0) & (xi < W);
      const float wgt = valid ? (dy2 ? fy : 1.f - fy) * (dx2 ? fx : 1.f - fx) * m : 0.f;
      const int yc = min(max(yi, 0), H - 1);    // interior clamp (unpadded coords)
      const int xc = min(max(xi, 0), W - 1);
      const int off = ((b * H + yc) * W + xc) * 32;   // uint4 units within a k-plane
      s_ow[ps][k][c2] = float2{__int_as_float(off), wgt};
    }
  }
  __syncthreads();

  const int p = bs * 8 + sub;
  float a[8] = {0.f, 0.f, 0.f, 0.f, 0.f, 0.f, 0.f, 0.f};

#pragma unroll 1
  for (int k = 0; k < 9; ++k) {
    const float2 ow0 = s_ow[sub][k][0], ow1 = s_ow[sub][k][1];
    const float2 ow2 = s_ow[sub][k][2], ow3 = s_ow[sub][k][3];
    const uint4* pk = G4 + (size_t)k * (NP * 32) + cid;
    acc8(pk[(size_t)__float_as_int(ow0.x)], ow0.y, a);
    acc8(pk[(size_t)__float_as_int(ow1.x)], ow1.y, a);
    acc8(pk[(size_t)__float_as_int(ow2.x)], ow2.y, a);
    acc8(pk[(size_t)__float_as_int(ow3.x)], ow3.y, a);
  }

  const float* bp = bias + cid * 8;
  float* op = out + (size_t)p * 256 + cid * 8;
  float4 o0 = {a[0] + bp[0], a[1] + bp[1], a[2] + bp[2], a[3] + bp[3]};
  float4 o1 = {a[4] + bp[4], a[5] + bp[5], a[6] + bp[6], a[7] + bp[7]};
  *(float4*)op = o0;
  *(float4*)(op + 4) = o1;
}

extern "C" void kernel_launch(void* const* d_in, const int* in_sizes, int n_in,
                              void* d_out, int out_size, void* d_ws, size_t ws_size,
                              hipStream_t stream) {
  const float* x    = (const float*)d_in[0];   // [4,96,96,256]
  const float* omk  = (const float*)d_in[1];   // [3,3,256,27]
  const float* omb  = (const float*)d_in[2];   // [27]
  const float* kern = (const float*)d_in[3];   // [2304,256]
  const float* bias = (const float*)d_in[4];   // [256]
  float* out = (float*)d_out;                  // [4,96,96,256]

  char* ws = (char*)d_ws;
  size_t off = 0;
  __hip_bfloat16* wt   = (__hip_bfloat16*)(ws + off); off += (size_t)F * KC * 2;           // 1,179,648
  __hip_bfloat16* xp   = (__hip_bfloat16*)(ws + off); off += (size_t)4 * HP * HP * C * 2;  // 19,668,992
  __hip_bfloat16* wom  = (__hip_bfloat16*)(ws + off); off += (size_t)32 * KC * 2;          // 147,456
  float*          pOm  = (float*)(ws + off);          off += (size_t)NP * 32 * 4;          // 4,718,592
  __hip_bfloat16* G    = (__hip_bfloat16*)(ws + off);                                      // 169,869,312 (== old cols)

  k_pad    <<<dim3(NB_PAD),          256, 0, stream>>>(x, (uint4*)xp);
  k_wprep  <<<dim3(NB_OMW + NB_WT),  256, 0, stream>>>(omk, kern, wom, wt);
  k_omgemm <<<dim3(576),             256, 0, stream>>>(xp, wom, pOm);
  k_gemmG  <<<dim3(288, 9),          512, 0, stream>>>(xp, wt, G);
  k_combine<<<dim3(NP / 8),          256, 0, stream>>>((const uint4*)G, pOm, omb, bias, out);
}